// Round 13
// baseline (833.172 us; speedup 1.0000x reference)
//
#include <hip/hip_runtime.h>

#define NW 12

typedef float f2 __attribute__((ext_vector_type(2)));

// data-movement source index for the 5-CNOT chain on 6 local bits
__device__ constexpr int perm64c(int j) {
    j ^= (j >> 1) & 1;
    j ^= (j >> 1) & 2;
    j ^= (j >> 1) & 4;
    j ^= (j >> 1) & 8;
    j ^= (j >> 1) & 16;
    return j;
}

// parity of j bits 5..(5-k)
__device__ constexpr int ppar(int j, int k) {
    int p = 0;
    for (int i = 0; i <= k; ++i) p ^= (j >> (5 - i)) & 1;
    return p;
}

__device__ __forceinline__ f2 sp(float x) { f2 v; v.x = x; v.y = x; return v; }

__device__ __forceinline__ float elv(const f2* A, int j) {
    return (j & 1) ? A[j >> 1].y : A[j >> 1].x;
}

// ---------------- RX butterfly on packed-pair distance PM ----------------
template<int PM>
__device__ __forceinline__ void rx_pk(f2* R, f2* I, f2 c, f2 s) {
    #pragma unroll
    for (int k0 = 0; k0 < 32; ++k0) {
        if (k0 & PM) continue;
        const int k1 = k0 | PM;
        const f2 ar = R[k0], ai = I[k0], br = R[k1], bi = I[k1];
        R[k0] = c * ar + s * bi;
        I[k0] = c * ai - s * br;
        R[k1] = c * br + s * ai;
        I[k1] = c * bi - s * ar;
    }
}

__device__ __forceinline__ void rx_pk0(f2* R, f2* I, f2 c, f2 s) {
    #pragma unroll
    for (int k = 0; k < 32; ++k) {
        const f2 Rs = R[k].yx, Is = I[k].yx;
        R[k] = c * R[k] + s * Is;
        I[k] = c * I[k] - s * Rs;
    }
}

__device__ __forceinline__ void rx_sweep(f2* R, f2* I, const float2* __restrict__ cs) {
    { const float2 q = cs[0]; rx_pk<16>(R, I, sp(q.x), sp(q.y)); }
    { const float2 q = cs[1]; rx_pk<8>(R, I, sp(q.x), sp(q.y)); }
    { const float2 q = cs[2]; rx_pk<4>(R, I, sp(q.x), sp(q.y)); }
    { const float2 q = cs[3]; rx_pk<2>(R, I, sp(q.x), sp(q.y)); }
    { const float2 q = cs[4]; rx_pk<1>(R, I, sp(q.x), sp(q.y)); }
    { const float2 q = cs[5]; rx_pk0(R, I, sp(q.x), sp(q.y)); }
}

// combined diagonal (6 RZs) in packed layout
__device__ __forceinline__ void diag_pk(f2* R, f2* I, const float4* __restrict__ z) {
    #pragma unroll
    for (int k = 0; k < 32; ++k) {
        const float4 q = z[k];
        f2 zx; zx.x = q.x; zx.y = q.y;
        f2 zy; zy.x = q.z; zy.y = q.w;
        const f2 nr = R[k] * zx - I[k] * zy;
        const f2 ni = I[k] * zx + R[k] * zy;
        R[k] = nr; I[k] = ni;
    }
}

// compile-time permutation (register renames)
__device__ __forceinline__ void perm_pk(f2* R, f2* I) {
    f2 tR[32], tI[32];
    #pragma unroll
    for (int k = 0; k < 32; ++k) {
        const int s0 = perm64c(2 * k);
        const int k2 = s0 >> 1;
        if (s0 & 1) { tR[k] = R[k2].yx; tI[k] = I[k2].yx; }
        else        { tR[k] = R[k2];    tI[k] = I[k2];    }
    }
    #pragma unroll
    for (int k = 0; k < 32; ++k) { R[k] = tR[k]; I[k] = tI[k]; }
}

// CNOT(5,6) in L2 layout
__device__ __forceinline__ void cnot56_L2(f2* R, f2* I) {
    #pragma unroll
    for (int k = 0; k < 32; ++k) {
        R[k].y = __shfl_xor(R[k].y, 32, 64);
        I[k].y = __shfl_xor(I[k].y, 32, 64);
    }
}

// CNOT(5,6) in L1 layout
__device__ __forceinline__ void cnot56_L1(f2* R, f2* I, int lane) {
    const bool c = (lane & 1) != 0;
    #pragma unroll
    for (int k = 0; k < 16; ++k) {
        const f2 a0 = R[k], a1 = R[k + 16], b0 = I[k], b1 = I[k + 16];
        R[k]      = c ? a1 : a0;  R[k + 16] = c ? a0 : a1;
        I[k]      = c ? b1 : b0;  I[k + 16] = c ? b0 : b1;
    }
}

// ---------------- in-wave 64x64 transpose via LDS (no barriers) ----------------
template<bool PRE, bool POST>
__device__ __forceinline__ void tpose(float* pl, f2* R, f2* I, const int lane, const int rb) {
    char* base = reinterpret_cast<char*>(pl);
    const int ls = lane & 15;
    const int wb = lane << 8;
    #pragma unroll
    for (int g = 0; g < 16; ++g) {
        float4 v;
        v.x = elv(R, PRE ? perm64c(4 * g + 0) : 4 * g + 0);
        v.y = elv(R, PRE ? perm64c(4 * g + 1) : 4 * g + 1);
        v.z = elv(R, PRE ? perm64c(4 * g + 2) : 4 * g + 2);
        v.w = elv(R, PRE ? perm64c(4 * g + 3) : 4 * g + 3);
        *reinterpret_cast<float4*>(base + wb + ((g ^ ls) << 4)) = v;
    }
    #pragma unroll
    for (int k = 0; k < 32; ++k) {
        const int r0 = POST ? perm64c(2 * k) : 2 * k;
        const int r1 = r0 ^ 1;
        f2 nv;
        nv.x = *reinterpret_cast<const float*>(base + (rb ^ (((r0 & 15) << 4) | (r0 << 8))));
        nv.y = *reinterpret_cast<const float*>(base + (rb ^ (((r1 & 15) << 4) | (r1 << 8))));
        R[k] = nv;
    }
    #pragma unroll
    for (int g = 0; g < 16; ++g) {
        float4 v;
        v.x = elv(I, PRE ? perm64c(4 * g + 0) : 4 * g + 0);
        v.y = elv(I, PRE ? perm64c(4 * g + 1) : 4 * g + 1);
        v.z = elv(I, PRE ? perm64c(4 * g + 2) : 4 * g + 2);
        v.w = elv(I, PRE ? perm64c(4 * g + 3) : 4 * g + 3);
        *reinterpret_cast<float4*>(base + wb + ((g ^ ls) << 4)) = v;
    }
    #pragma unroll
    for (int k = 0; k < 32; ++k) {
        const int r0 = POST ? perm64c(2 * k) : 2 * k;
        const int r1 = r0 ^ 1;
        f2 nv;
        nv.x = *reinterpret_cast<const float*>(base + (rb ^ (((r0 & 15) << 4) | (r0 << 8))));
        nv.y = *reinterpret_cast<const float*>(base + (rb ^ (((r1 & 15) << 4) | (r1 << 8))));
        I[k] = nv;
    }
}

// ---------------- precompute (batch-uniform gate constants) ----------------
__global__ void qr_pre(const float* __restrict__ params,
                       float2* __restrict__ tabcs,   // [8][6]
                       float* __restrict__ zpk)      // [6][32][4]
{
    const int t = threadIdx.x;
    if (t < 48) {
        const int h = t / 6, k = t - h * 6;
        const int l = h >> 1;
        const int base = (((h & 3) == 0) || ((h & 3) == 3)) ? 6 : 0;
        const float th = 0.5f * params[l * 12 + base + k];
        tabcs[t] = make_float2(cosf(th), sinf(th));
    }
    if (t < 384) {
        const int h = t >> 6, j = t & 63;
        const int l = h >> 1;
        const int base = (((h & 3) == 0) || ((h & 3) == 3)) ? 6 : 0;
        float pr = 1.f, pi = 0.f;
        for (int k = 0; k < 6; ++k) {
            const float th = 0.5f * params[l * 12 + base + k];
            const float c = cosf(th), s = sinf(th);
            const float ss = (j & (32 >> k)) ? s : -s;
            const float nr = pr * c - pi * ss;
            pi = pr * ss + pi * c;
            pr = nr;
        }
        float* q = zpk + (h * 32 + (j >> 1)) * 4;
        q[j & 1] = pr;
        q[2 + (j & 1)] = pi;
    }
}

// ---------------- main: 1 wave = 2 samples (ILP-2) ----------------
// r12 refuted dispatch-churn: persistent blocks left occupancy at 11.3%
// (~0.9 waves/SIMD) and dur at 452us. The machine runs ~1 wave/SIMD for this
// kernel; the 45% VALU-idle is intra-wave latency (LDS transpose, s_load,
// dep chains). Fix via ILP: two independent samples per wave -> an issueable
// instruction in nearly every stall slot. State 2x128=256 VGPR + ~60 misc
// fits the 512 cap (launch_bounds(64,1); r6 lesson: never tighten the cap).
// Separate 16 KiB LDS halves keep the two transpose streams independent.
__global__ __launch_bounds__(64, 1) void qr_main(
    const float* __restrict__ inputs,
    const float2* __restrict__ tabcs,
    const float4* __restrict__ zpk,
    const float* __restrict__ head_w,
    const float* __restrict__ head_b,
    float* __restrict__ out)
{
    __shared__ __align__(16) float pl[8192];   // 32 KiB: 16 KiB per sample
    const int lane = threadIdx.x;
    const int b0 = blockIdx.x * 2;

    const int rb = (((lane >> 2) << 4) | ((lane & 3) << 2));

    // sample-invariant measurement constants
    float w[12];
    #pragma unroll
    for (int i = 0; i < 12; ++i) w[i] = head_w[i];
    const float hb = head_b[0];

    float C = 0.f; int par = 0;
    #pragma unroll
    for (int i = 0; i < 6; ++i) {
        par ^= (lane >> (5 - i)) & 1;
        C += par ? -w[i] : w[i];
    }
    const float sg = par ? -1.f : 1.f;

    // ---- init both samples ----
    f2 Ra[32], Ia[32], Rb[32], Ib[32];
    {
        float cy[12], sy[12];
        #pragma unroll
        for (int i = 0; i < 12; ++i)
            __sincosf(0.5f * inputs[b0 * 12 + i], &sy[i], &cy[i]);
        float F = 1.f;
        #pragma unroll
        for (int i = 0; i < 6; ++i) F *= (lane & (32 >> i)) ? sy[i] : cy[i];
        float hi[8];
        #pragma unroll
        for (int m = 0; m < 8; ++m)
            hi[m] = ((m & 4) ? sy[6] : cy[6]) * ((m & 2) ? sy[7] : cy[7]) * ((m & 1) ? sy[8] : cy[8]);
        f2 lop[4];
        #pragma unroll
        for (int m = 0; m < 4; ++m) {
            const float q = ((m & 2) ? sy[9] : cy[9]) * ((m & 1) ? sy[10] : cy[10]);
            lop[m].x = q * cy[11];
            lop[m].y = q * sy[11];
        }
        #pragma unroll
        for (int k = 0; k < 32; ++k) { Ra[k] = sp(F * hi[k >> 2]) * lop[k & 3]; Ia[k] = sp(0.f); }
    }
    {
        float cy[12], sy[12];
        #pragma unroll
        for (int i = 0; i < 12; ++i)
            __sincosf(0.5f * inputs[(b0 + 1) * 12 + i], &sy[i], &cy[i]);
        float F = 1.f;
        #pragma unroll
        for (int i = 0; i < 6; ++i) F *= (lane & (32 >> i)) ? sy[i] : cy[i];
        float hi[8];
        #pragma unroll
        for (int m = 0; m < 8; ++m)
            hi[m] = ((m & 4) ? sy[6] : cy[6]) * ((m & 2) ? sy[7] : cy[7]) * ((m & 1) ? sy[8] : cy[8]);
        f2 lop[4];
        #pragma unroll
        for (int m = 0; m < 4; ++m) {
            const float q = ((m & 2) ? sy[9] : cy[9]) * ((m & 1) ? sy[10] : cy[10]);
            lop[m].x = q * cy[11];
            lop[m].y = q * sy[11];
        }
        #pragma unroll
        for (int k = 0; k < 32; ++k) { Rb[k] = sp(F * hi[k >> 2]) * lop[k & 3]; Ib[k] = sp(0.f); }
    }

    // ---- 8 half-layers, both samples interleaved by the scheduler ----
    #pragma unroll 1
    for (int h = 0; h < 8; ++h) {
        rx_sweep(Ra, Ia, tabcs + h * 6);
        rx_sweep(Rb, Ib, tabcs + h * 6);
        if (h < 6) {
            diag_pk(Ra, Ia, zpk + h * 32);
            diag_pk(Rb, Ib, zpk + h * 32);
        }

        if (h == 1 || h == 5) {
            perm_pk(Ra, Ia); cnot56_L2(Ra, Ia);
            perm_pk(Rb, Ib); cnot56_L2(Rb, Ib);
        } else if (h == 3) {
            cnot56_L1(Ra, Ia, lane); perm_pk(Ra, Ia);
            cnot56_L1(Rb, Ib, lane); perm_pk(Rb, Ib);
        } else if (h == 0 || h == 4) {
            tpose<false, false>(pl, Ra, Ia, lane, rb);
            tpose<false, false>(pl + 4096, Rb, Ib, lane, rb);
        } else if (h == 2) {
            tpose<true, true>(pl, Ra, Ia, lane, rb);
            tpose<true, true>(pl + 4096, Rb, Ib, lane, rb);
        } else if (h == 6) {
            tpose<false, true>(pl, Ra, Ia, lane, rb);
            tpose<false, true>(pl + 4096, Rb, Ib, lane, rb);
        }
    }

    // ---- measurement (both samples) ----
    float phiA = 0.f, phiB = 0.f;
    #pragma unroll
    for (int j = 0; j < 64; ++j) {
        float D = 0.f;
        #pragma unroll
        for (int k = 0; k < 6; ++k)
            D += ppar(j, k) ? -w[6 + k] : w[6 + k];
        const float cj = C + sg * D;
        {
            const float re = elv(Ra, j), im = elv(Ia, j);
            phiA += cj * (re * re + im * im);
        }
        {
            const float re = elv(Rb, j), im = elv(Ib, j);
            phiB += cj * (re * re + im * im);
        }
    }

    #pragma unroll
    for (int m = 32; m; m >>= 1) {
        phiA += __shfl_xor(phiA, m, 64);
        phiB += __shfl_xor(phiB, m, 64);
    }
    if (lane == 0) {
        out[b0]     = phiA + hb;
        out[b0 + 1] = phiB + hb;
    }
}

extern "C" void kernel_launch(void* const* d_in, const int* in_sizes, int n_in,
                              void* d_out, int out_size, void* d_ws, size_t ws_size,
                              hipStream_t stream) {
    const float* inputs = (const float*)d_in[0];
    const float* params = (const float*)d_in[1];
    const float* head_w = (const float*)d_in[2];
    const float* head_b = (const float*)d_in[3];
    float* out = (float*)d_out;

    float2* tabcs = (float2*)d_ws;                 // 48 float2 = 384 B
    float*  zpk   = (float*)d_ws + 96;             // 6*32 float4 = 3072 B

    const int batch = in_sizes[0] / NW;

    qr_pre<<<1, 384, 0, stream>>>(params, tabcs, zpk);
    qr_main<<<batch / 2, 64, 0, stream>>>(inputs, tabcs, (const float4*)zpk, head_w, head_b, out);
}